// Round 7
// baseline (10721.333 us; speedup 1.0000x reference)
//
#include <hip/hip_runtime.h>
#include <math.h>

#define Dh 1024
#define Tt 4096
#define NB 128      // recurrence blocks; each owns 8 output columns
#define NCOPY 16    // replicated h-exchange copies (contention reduction)

// ---------------------------------------------------------------------------
// GEMM: C[M x N](ldc) = op(A[M x K]) @ B[K x N] + bias [+ resid]
// 64x64 tile, BK=16, 256 threads, 4x4 micro-tile per thread. fp32.
// ---------------------------------------------------------------------------
template<bool RELU, bool RESID>
__global__ __launch_bounds__(256)
void gemm64(const float* __restrict__ A, const float* __restrict__ B,
            const float* __restrict__ bias, const float* __restrict__ resid,
            float* __restrict__ C, int M, int N, int K, int ldc)
{
    __shared__ __align__(16) float As[16][68];   // [k][m], padded row
    __shared__ __align__(16) float Bs[16][64];   // [k][n]
    const int tid = threadIdx.x;
    const int tx = tid & 15, ty = tid >> 4;
    const int bn = blockIdx.x * 64, bm = blockIdx.y * 64;

    const int lm = tid >> 2, lk = (tid & 3) * 4;     // A tile load coords
    const int bk = tid >> 4, bn4 = (tid & 15) * 4;   // B tile load coords

    float acc[4][4] = {};

    for (int k0 = 0; k0 < K; k0 += 16) {
        float4 av = *(const float4*)(A + (size_t)(bm + lm) * K + k0 + lk);
        if (RELU) {
            av.x = fmaxf(av.x, 0.f); av.y = fmaxf(av.y, 0.f);
            av.z = fmaxf(av.z, 0.f); av.w = fmaxf(av.w, 0.f);
        }
        As[lk + 0][lm] = av.x; As[lk + 1][lm] = av.y;
        As[lk + 2][lm] = av.z; As[lk + 3][lm] = av.w;
        *(float4*)&Bs[bk][bn4] = *(const float4*)(B + (size_t)(k0 + bk) * N + bn + bn4);
        __syncthreads();
        #pragma unroll
        for (int kk = 0; kk < 16; ++kk) {
            float4 a4 = *(const float4*)&As[kk][ty * 4];
            float4 b4 = *(const float4*)&Bs[kk][tx * 4];
            acc[0][0] += a4.x * b4.x; acc[0][1] += a4.x * b4.y; acc[0][2] += a4.x * b4.z; acc[0][3] += a4.x * b4.w;
            acc[1][0] += a4.y * b4.x; acc[1][1] += a4.y * b4.y; acc[1][2] += a4.y * b4.z; acc[1][3] += a4.y * b4.w;
            acc[2][0] += a4.z * b4.x; acc[2][1] += a4.z * b4.y; acc[2][2] += a4.z * b4.z; acc[2][3] += a4.z * b4.w;
            acc[3][0] += a4.w * b4.x; acc[3][1] += a4.w * b4.y; acc[3][2] += a4.w * b4.z; acc[3][3] += a4.w * b4.w;
        }
        __syncthreads();
    }

    const float4 bias4 = *(const float4*)(bias + bn + tx * 4);
    #pragma unroll
    for (int i = 0; i < 4; ++i) {
        const int row = bm + ty * 4 + i;
        float4 o;
        o.x = acc[i][0] + bias4.x; o.y = acc[i][1] + bias4.y;
        o.z = acc[i][2] + bias4.z; o.w = acc[i][3] + bias4.w;
        if (RESID) {
            const float4 r4 = *(const float4*)(resid + (size_t)row * N + bn + tx * 4);
            o.x += r4.x; o.y += r4.y; o.z += r4.z; o.w += r4.w;
        }
        *(float4*)(C + (size_t)row * ldc + bn + tx * 4) = o;
    }
}

// ---------------------------------------------------------------------------
// Fast activations — tolerance is 0.099 absmax; native exp/rcp are ~1e-6 rel.
// ---------------------------------------------------------------------------
__device__ __forceinline__ float fast_sigmoid(float x)
{
    return __builtin_amdgcn_rcpf(1.f + __expf(-x));
}
__device__ __forceinline__ float fast_tanh(float x)
{
    x = fminf(15.f, fmaxf(-15.f, x));
    const float e2 = __expf(2.f * x);
    return (e2 - 1.f) * __builtin_amdgcn_rcpf(e2 + 1.f);
}

// ---------------------------------------------------------------------------
// Pack init_state into ALL NCOPY copies of buffer 0: {tag=0 : value}
// ---------------------------------------------------------------------------
__global__ __launch_bounds__(256)
void pack_h0(const float* __restrict__ h0, unsigned long long* __restrict__ buf)
{
    const int idx = blockIdx.x * 256 + threadIdx.x;   // 0 .. NCOPY*Dh-1
    const int slot = idx & (Dh - 1);
    __hip_atomic_store(buf + idx, (unsigned long long)__float_as_uint(h0[slot]),
                       __ATOMIC_RELAXED, __HIP_MEMORY_SCOPE_AGENT);
}

// ---------------------------------------------------------------------------
// Sequential GRU scan. 128 blocks x 320 threads (4 compute waves + 1 I/O
// wave), all co-resident. Block b owns columns [8b, 8b+8); one 32-lane group
// per column; weights register-resident (96 floats/thread).
//
// Single-hop sync with REPLICATED exchange buffers: producers publish their
// 8 {tag,val} slots into NCOPY=16 copies; block b polls only copy b>>3.
// Per-line poller count drops 1024 -> 64, cutting the MALL same-line service
// queue that dominated detection latency in rounds 3-6.
//
// Critical-path invariant: compute waves issue ZERO global ops except the
// poll loads. Wave 4 does ALL other global I/O (publish x16 copies, ys row
// store, xproj prefetch into LDS); its acks drain in pre-B1 slack.
// ---------------------------------------------------------------------------
__global__ __launch_bounds__(320, 1)
void gru_rec(const float* __restrict__ xproj,   // [T][3*Dh]  (r,z,n) incl. input bias
             const float* __restrict__ Whr, const float* __restrict__ Whz,
             const float* __restrict__ Whn, const float* __restrict__ bhn,
             float* __restrict__ ys,            // [T][Dh]
             unsigned long long* __restrict__ mbox)   // [2][NCOPY][Dh] packed {tag,val}
{
    const int b = blockIdx.x, tid = threadIdx.x;
    const bool is_compute = tid < 256;
    const int g = tid >> 5;        // group 0..7 -> local column (compute waves)
    const int i = tid & 31;        // lane in group
    const int col = b * 8 + g;

    __shared__ __align__(16) float h_lds[Dh];
    __shared__ float hnew_lds[8];
    __shared__ float xp_lds[24];   // row t: [0..7]=r, [8..15]=z, [16..23]=n

    // Register-resident weight slice: rows r = 4i + 128j + k
    float wr[32], wz[32], wn[32];
    float bhn_c = 0.f;
    if (is_compute) {
        #pragma unroll
        for (int j = 0; j < 8; ++j)
            #pragma unroll
            for (int k = 0; k < 4; ++k) {
                const int r = 4 * i + 128 * j + k;
                wr[j * 4 + k] = Whr[(size_t)r * Dh + col];
                wz[j * 4 + k] = Whz[(size_t)r * Dh + col];
                wn[j * 4 + k] = Whn[(size_t)r * Dh + col];
            }
        bhn_c = bhn[col];
    } else {
        // preload xproj row 0: lane l -> gate j=l>>3, col g=l&7
        const int lane = tid - 256;
        if (lane < 24)
            xp_lds[lane] = xproj[(size_t)(lane >> 3) * Dh + b * 8 + (lane & 7)];
    }
    __syncthreads();   // B0: xp_lds row 0 ready; weights loaded

    const int mycopy = b >> 3;     // 8 blocks share each copy

    for (int t = 0; t < Tt; ++t) {
        const unsigned long long* src =
            mbox + (size_t)(t & 1) * (NCOPY * Dh) + (size_t)mycopy * Dh;
        unsigned long long* dstbase = mbox + (size_t)((t + 1) & 1) * (NCOPY * Dh);
        const unsigned int want = (unsigned int)t;

        float4 y0, y1, y2, y3;   // wave4's h_t slice (contiguous, for ys store)

        if (is_compute) {
            // ---- single-hop poll: 4 strided slots, tag==t means valid ----
            unsigned long long p0, p1, p2, p3;
            int tries = 0;
            for (;;) {
                p0 = __hip_atomic_load(src + tid +   0, __ATOMIC_RELAXED, __HIP_MEMORY_SCOPE_AGENT);
                p1 = __hip_atomic_load(src + tid + 256, __ATOMIC_RELAXED, __HIP_MEMORY_SCOPE_AGENT);
                p2 = __hip_atomic_load(src + tid + 512, __ATOMIC_RELAXED, __HIP_MEMORY_SCOPE_AGENT);
                p3 = __hip_atomic_load(src + tid + 768, __ATOMIC_RELAXED, __HIP_MEMORY_SCOPE_AGENT);
                unsigned int bad = ((unsigned int)(p0 >> 32)) ^ want;
                bad |= ((unsigned int)(p1 >> 32)) ^ want;
                bad |= ((unsigned int)(p2 >> 32)) ^ want;
                bad |= ((unsigned int)(p3 >> 32)) ^ want;
                if (!bad) break;
                if (++tries > 6) __builtin_amdgcn_s_sleep(1);
            }
            h_lds[tid +   0] = __uint_as_float((unsigned int)p0);
            h_lds[tid + 256] = __uint_as_float((unsigned int)p1);
            h_lds[tid + 512] = __uint_as_float((unsigned int)p2);
            h_lds[tid + 768] = __uint_as_float((unsigned int)p3);
        }
        __syncthreads();                       // B1: h_lds = h_t complete

        if (is_compute) {
            // ---- dot products from LDS against register weights ----
            float ar = 0.f, az = 0.f, an = 0.f;
            const float4* h4 = (const float4*)h_lds;
            #pragma unroll
            for (int j = 0; j < 8; ++j) {
                const float4 hv = h4[i + j * 32];
                ar += hv.x * wr[4*j] + hv.y * wr[4*j+1] + hv.z * wr[4*j+2] + hv.w * wr[4*j+3];
                az += hv.x * wz[4*j] + hv.y * wz[4*j+1] + hv.z * wz[4*j+2] + hv.w * wz[4*j+3];
                an += hv.x * wn[4*j] + hv.y * wn[4*j+1] + hv.z * wn[4*j+2] + hv.w * wn[4*j+3];
            }
            #pragma unroll
            for (int off = 16; off > 0; off >>= 1) {
                ar += __shfl_down(ar, off, 32);
                az += __shfl_down(az, off, 32);
                an += __shfl_down(an, off, 32);
            }

            if (i == 0) {
                const float xr = xp_lds[g], xz = xp_lds[8 + g], xn = xp_lds[16 + g];
                const float r = fast_sigmoid(xr + ar);
                const float z = fast_sigmoid(xz + az);
                const float n = fast_tanh(xn + r * (an + bhn_c));
                const float hp = h_lds[col];
                hnew_lds[g] = (1.f - z) * n + z * hp;   // hand off to I/O wave
            }
        } else {
            // wave4: contiguous, conflict-free snapshot of h_t (for ys store)
            const int lane = tid - 256;
            const float4* hr = (const float4*)h_lds;
            y0 = hr[lane]; y1 = hr[lane + 64]; y2 = hr[lane + 128]; y3 = hr[lane + 192];
        }
        __syncthreads();                       // B2: hnew_lds complete

        if (!is_compute) {
            const int lane = tid - 256;
            // 1) publish block's 8 slots into all NCOPY copies:
            //    lane l -> copy l>>2, slots (l&3)*2 and (l&3)*2+1
            {
                const int cp = lane >> 2, j2 = (lane & 3) * 2;
                unsigned long long* dst = dstbase + (size_t)cp * Dh + b * 8 + j2;
                const unsigned long long taghi =
                    ((unsigned long long)(unsigned int)(t + 1) << 32);
                const unsigned long long pk0 =
                    taghi | (unsigned long long)__float_as_uint(hnew_lds[j2]);
                const unsigned long long pk1 =
                    taghi | (unsigned long long)__float_as_uint(hnew_lds[j2 + 1]);
                __hip_atomic_store(dst + 0, pk0, __ATOMIC_RELAXED, __HIP_MEMORY_SCOPE_AGENT);
                __hip_atomic_store(dst + 1, pk1, __ATOMIC_RELAXED, __HIP_MEMORY_SCOPE_AGENT);
            }
            // 2) ys[t-1] = h_t row store (coalesced 1KB per pass)
            if (t > 0) {
                float4* yrow = (float4*)(ys + (size_t)(t - 1) * Dh);
                yrow[lane] = y0; yrow[lane + 64] = y1;
                yrow[lane + 128] = y2; yrow[lane + 192] = y3;
            }
            // 3) prefetch xproj row t+1 into xp_lds (readers use it only
            //    after B1(t+1); ordered by B2(t) and B1(t+1))
            if (lane < 24 && t + 1 < Tt) {
                xp_lds[lane] = xproj[(size_t)(t + 1) * (3 * Dh)
                                     + (size_t)(lane >> 3) * Dh + b * 8 + (lane & 7)];
            }
            // all acks/misses drain in this wave's pre-B1(t+1) slack
        }
    }

    // final row: ys[Tt-1] = h_Tt (tag Tt lives in buffer Tt&1 = 0, copy 0;
    // block 0 polls copy 0)
    if (b == 0 && is_compute) {
        const unsigned long long* src = mbox + (size_t)(Tt & 1) * (NCOPY * Dh);
        const unsigned int want = (unsigned int)Tt;
        unsigned long long p0, p1, p2, p3;
        for (;;) {
            p0 = __hip_atomic_load(src + tid +   0, __ATOMIC_RELAXED, __HIP_MEMORY_SCOPE_AGENT);
            p1 = __hip_atomic_load(src + tid + 256, __ATOMIC_RELAXED, __HIP_MEMORY_SCOPE_AGENT);
            p2 = __hip_atomic_load(src + tid + 512, __ATOMIC_RELAXED, __HIP_MEMORY_SCOPE_AGENT);
            p3 = __hip_atomic_load(src + tid + 768, __ATOMIC_RELAXED, __HIP_MEMORY_SCOPE_AGENT);
            unsigned int bad = ((unsigned int)(p0 >> 32)) ^ want;
            bad |= ((unsigned int)(p1 >> 32)) ^ want;
            bad |= ((unsigned int)(p2 >> 32)) ^ want;
            bad |= ((unsigned int)(p3 >> 32)) ^ want;
            if (!bad) break;
        }
        float* yrow = ys + (size_t)(Tt - 1) * Dh;
        yrow[tid +   0] = __uint_as_float((unsigned int)p0);
        yrow[tid + 256] = __uint_as_float((unsigned int)p1);
        yrow[tid + 512] = __uint_as_float((unsigned int)p2);
        yrow[tid + 768] = __uint_as_float((unsigned int)p3);
    }
}

// ---------------------------------------------------------------------------
// In-place layernorm over rows of y [T][Dh], matching jnp mean/var, eps=1e-6
// ---------------------------------------------------------------------------
__global__ __launch_bounds__(256)
void layernorm_ip(float* __restrict__ y, const float* __restrict__ sc,
                  const float* __restrict__ bi)
{
    __shared__ float red[8], red2[8], stat[2];
    const int row = blockIdx.x, tid = threadIdx.x;
    float4* yr = (float4*)(y + (size_t)row * Dh);
    float4 v = yr[tid];
    float s  = v.x + v.y + v.z + v.w;
    float s2 = v.x*v.x + v.y*v.y + v.z*v.z + v.w*v.w;
    #pragma unroll
    for (int off = 32; off > 0; off >>= 1) {
        s  += __shfl_down(s,  off);
        s2 += __shfl_down(s2, off);
    }
    if ((tid & 63) == 0) { red[tid >> 6] = s; red2[tid >> 6] = s2; }
    __syncthreads();
    if (tid == 0) {
        float ts = 0.f, t2 = 0.f;
        #pragma unroll
        for (int w = 0; w < 4; ++w) { ts += red[w]; t2 += red2[w]; }
        const float mu  = ts / (float)Dh;
        const float var = t2 / (float)Dh - mu * mu;
        stat[0] = mu;
        stat[1] = rsqrtf(var + 1e-6f);
    }
    __syncthreads();
    const float mu = stat[0], rstd = stat[1];
    const float4 s4 = ((const float4*)sc)[tid];
    const float4 b4 = ((const float4*)bi)[tid];
    v.x = (v.x - mu) * rstd * s4.x + b4.x;
    v.y = (v.y - mu) * rstd * s4.y + b4.y;
    v.z = (v.z - mu) * rstd * s4.z + b4.z;
    v.w = (v.w - mu) * rstd * s4.w + b4.w;
    yr[tid] = v;
}

// ---------------------------------------------------------------------------
extern "C" void kernel_launch(void* const* d_in, const int* in_sizes, int n_in,
                              void* d_out, int out_size, void* d_ws, size_t ws_size,
                              hipStream_t stream)
{
    const float* xs   = (const float*)d_in[0];
    const float* h0   = (const float*)d_in[1];
    const float* Wir  = (const float*)d_in[2];
    const float* Wiz  = (const float*)d_in[3];
    const float* Win  = (const float*)d_in[4];
    const float* bir  = (const float*)d_in[5];
    const float* biz  = (const float*)d_in[6];
    const float* bin_ = (const float*)d_in[7];
    const float* Whr  = (const float*)d_in[8];
    const float* Whz  = (const float*)d_in[9];
    const float* Whn  = (const float*)d_in[10];
    const float* bhn  = (const float*)d_in[11];
    const float* Wl   = (const float*)d_in[12];
    const float* bl   = (const float*)d_in[13];
    const float* ln_s = (const float*)d_in[14];
    const float* ln_b = (const float*)d_in[15];
    float* out = (float*)d_out;

    // workspace layout
    float* xproj = (float*)d_ws;                               // T*3*Dh
    float* ys    = xproj + (size_t)Tt * 3 * Dh;                // T*Dh
    unsigned long long* mbox = (unsigned long long*)(ys + (size_t)Tt * Dh); // 2*NCOPY*Dh

    // Phase 0: pack init state (tag 0) into all copies of buffer 0
    pack_h0<<<(NCOPY * Dh) / 256, 256, 0, stream>>>(h0, mbox);

    // Phase 1: input projections (bias folded in)
    dim3 ggrid(Dh / 64, Tt / 64);
    gemm64<false, false><<<ggrid, 256, 0, stream>>>(xs, Wir, bir, nullptr,
                                                    xproj + 0 * Dh, Tt, Dh, Dh, 3 * Dh);
    gemm64<false, false><<<ggrid, 256, 0, stream>>>(xs, Wiz, biz, nullptr,
                                                    xproj + 1 * Dh, Tt, Dh, Dh, 3 * Dh);
    gemm64<false, false><<<ggrid, 256, 0, stream>>>(xs, Win, bin_, nullptr,
                                                    xproj + 2 * Dh, Tt, Dh, Dh, 3 * Dh);

    // Phase 2: sequential scan (persistent, co-resident grid)
    gru_rec<<<NB, 320, 0, stream>>>(xproj, Whr, Whz, Whn, bhn, ys, mbox);

    // Phase 3: out = relu(ys) @ Wl + bl + xs, then in-place layernorm
    gemm64<true, true><<<ggrid, 256, 0, stream>>>(ys, Wl, bl, xs, out, Tt, Dh, Dh, Dh);
    layernorm_ip<<<Tt, 256, 0, stream>>>(out, ln_s, ln_b);
}

// Round 8
// 10041.093 us; speedup vs baseline: 1.0677x; 1.0677x over previous
//
#include <hip/hip_runtime.h>
#include <math.h>

#define Dh 1024
#define Tt 4096
#define NB 128   // recurrence blocks; each owns 8 output columns

// ---------------------------------------------------------------------------
// GEMM: C[M x N](ldc) = op(A[M x K]) @ B[K x N] + bias [+ resid]
// ---------------------------------------------------------------------------
template<bool RELU, bool RESID>
__global__ __launch_bounds__(256)
void gemm64(const float* __restrict__ A, const float* __restrict__ B,
            const float* __restrict__ bias, const float* __restrict__ resid,
            float* __restrict__ C, int M, int N, int K, int ldc)
{
    __shared__ __align__(16) float As[16][68];
    __shared__ __align__(16) float Bs[16][64];
    const int tid = threadIdx.x;
    const int tx = tid & 15, ty = tid >> 4;
    const int bn = blockIdx.x * 64, bm = blockIdx.y * 64;

    const int lm = tid >> 2, lk = (tid & 3) * 4;
    const int bk = tid >> 4, bn4 = (tid & 15) * 4;

    float acc[4][4] = {};

    for (int k0 = 0; k0 < K; k0 += 16) {
        float4 av = *(const float4*)(A + (size_t)(bm + lm) * K + k0 + lk);
        if (RELU) {
            av.x = fmaxf(av.x, 0.f); av.y = fmaxf(av.y, 0.f);
            av.z = fmaxf(av.z, 0.f); av.w = fmaxf(av.w, 0.f);
        }
        As[lk + 0][lm] = av.x; As[lk + 1][lm] = av.y;
        As[lk + 2][lm] = av.z; As[lk + 3][lm] = av.w;
        *(float4*)&Bs[bk][bn4] = *(const float4*)(B + (size_t)(k0 + bk) * N + bn + bn4);
        __syncthreads();
        #pragma unroll
        for (int kk = 0; kk < 16; ++kk) {
            float4 a4 = *(const float4*)&As[kk][ty * 4];
            float4 b4 = *(const float4*)&Bs[kk][tx * 4];
            acc[0][0] += a4.x * b4.x; acc[0][1] += a4.x * b4.y; acc[0][2] += a4.x * b4.z; acc[0][3] += a4.x * b4.w;
            acc[1][0] += a4.y * b4.x; acc[1][1] += a4.y * b4.y; acc[1][2] += a4.y * b4.z; acc[1][3] += a4.y * b4.w;
            acc[2][0] += a4.z * b4.x; acc[2][1] += a4.z * b4.y; acc[2][2] += a4.z * b4.z; acc[2][3] += a4.z * b4.w;
            acc[3][0] += a4.w * b4.x; acc[3][1] += a4.w * b4.y; acc[3][2] += a4.w * b4.z; acc[3][3] += a4.w * b4.w;
        }
        __syncthreads();
    }

    const float4 bias4 = *(const float4*)(bias + bn + tx * 4);
    #pragma unroll
    for (int i = 0; i < 4; ++i) {
        const int row = bm + ty * 4 + i;
        float4 o;
        o.x = acc[i][0] + bias4.x; o.y = acc[i][1] + bias4.y;
        o.z = acc[i][2] + bias4.z; o.w = acc[i][3] + bias4.w;
        if (RESID) {
            const float4 r4 = *(const float4*)(resid + (size_t)row * N + bn + tx * 4);
            o.x += r4.x; o.y += r4.y; o.z += r4.z; o.w += r4.w;
        }
        *(float4*)(C + (size_t)row * ldc + bn + tx * 4) = o;
    }
}

// ---------------------------------------------------------------------------
__device__ __forceinline__ float fast_sigmoid(float x)
{
    return __builtin_amdgcn_rcpf(1.f + __expf(-x));
}
__device__ __forceinline__ float fast_tanh(float x)
{
    x = fminf(15.f, fmaxf(-15.f, x));
    const float e2 = __expf(2.f * x);
    return (e2 - 1.f) * __builtin_amdgcn_rcpf(e2 + 1.f);
}

// ---------------------------------------------------------------------------
// Pack init_state into epoch-tagged slots: {tag=0 : value} in buf[0]
// ---------------------------------------------------------------------------
__global__ __launch_bounds__(256)
void pack_h0(const float* __restrict__ h0, unsigned long long* __restrict__ buf)
{
    const int idx = blockIdx.x * 256 + threadIdx.x;   // 0..1023
    __hip_atomic_store(buf + idx, (unsigned long long)__float_as_uint(h0[idx]),
                       __ATOMIC_RELAXED, __HIP_MEMORY_SCOPE_AGENT);
}

// ---------------------------------------------------------------------------
// Sequential GRU scan — BARRIER-FREE wave-specialized pipeline.
// 128 blocks x 384 threads (6 waves), all co-resident.
//   W0   : global poller. Only wave touching hbuf reads. 16 tagged slots/lane
//          (l+64k) covers all 1024; stages to h_lds; LDS flag release.
//   W1-4 : compute. Spin LDS flag (lgkm only, no vmcnt!), ds_read h, dot with
//          reg-resident weights (2 cols/wave, float2[16] x 3 gates), 64-lane
//          butterfly reduce, activations in lanes 0/1, LDS outbox release.
//          ZERO global memory operations.
//   W5   : I/O. Spin outbox, publish 8 slots (one 64B line) to hbuf[(t+1)&1],
//          write ys[t] (own 32B, coalesced), prefetch xproj row t+1 -> LDS.
//          Its store-acks drain in its own spin; coupled to no one.
// No __syncthreads in the loop: no cross-wave vmcnt drains.
// Deadlock-free: publishing t+1 requires all tags==t, which requires every
// block finished reading parity t-1 (induction as in rounds 3-7).
// ---------------------------------------------------------------------------
__global__ __launch_bounds__(384, 1)
void gru_rec(const float* __restrict__ xproj,   // [T][3*Dh] (r,z,n) incl. input bias
             const float* __restrict__ Whr, const float* __restrict__ Whz,
             const float* __restrict__ Whn, const float* __restrict__ bhn,
             float* __restrict__ ys,            // [T][Dh]
             unsigned long long* __restrict__ hbuf)  // [2][Dh] packed {tag,val}
{
    const int b = blockIdx.x, tid = threadIdx.x;
    const int w = tid >> 6;       // wave 0..5
    const int l = tid & 63;       // lane

    __shared__ __align__(16) float h_lds[Dh];
    __shared__ unsigned long long outbox[8];   // {tag,val} per local col
    __shared__ float xp_lds[24];               // row t: [0..7]=r [8..15]=z [16..23]=n
    __shared__ int h_flag;                     // epoch staged in h_lds

    if (tid == 0) h_flag = -1;
    if (tid < 8)  outbox[tid] = 0;             // first wanted outbox tag is 1

    // ---------------- role-specific setup ----------------
    // compute waves: cw = w-1 in 0..3, cols c0 = b*8 + 2*cw, c0+1
    float2 wr[16], wz[16], wn[16], bhn2;
    const int cw = w - 1;
    const int c0 = b * 8 + cw * 2;
    if (w >= 1 && w <= 4) {
        #pragma unroll
        for (int k = 0; k < 16; ++k) {
            const int r = l + 64 * k;
            wr[k] = *(const float2*)(Whr + (size_t)r * Dh + c0);
            wz[k] = *(const float2*)(Whz + (size_t)r * Dh + c0);
            wn[k] = *(const float2*)(Whn + (size_t)r * Dh + c0);
        }
        bhn2 = *(const float2*)(bhn + c0);
    }
    if (w == 5 && l < 24) {       // xproj row 0: lane l -> gate l>>3, col l&7
        xp_lds[l] = xproj[(size_t)(l >> 3) * Dh + b * 8 + (l & 7)];
    }
    __syncthreads();   // one-time init barrier (outside steady loop)

    if (w == 0) {
        // =================== POLLER WAVE ===================
        for (int t = 0; t < Tt; ++t) {
            const unsigned long long* src = hbuf + (size_t)(t & 1) * Dh;
            const unsigned int want = (unsigned int)t;
            unsigned long long p[16];
            int tries = 0;
            for (;;) {
                #pragma unroll
                for (int k = 0; k < 16; ++k)
                    p[k] = __hip_atomic_load(src + l + 64 * k,
                                             __ATOMIC_RELAXED, __HIP_MEMORY_SCOPE_AGENT);
                unsigned int bad = 0;
                #pragma unroll
                for (int k = 0; k < 16; ++k)
                    bad |= ((unsigned int)(p[k] >> 32)) ^ want;
                if (!bad) break;
                if (++tries > 6) __builtin_amdgcn_s_sleep(1);
            }
            #pragma unroll
            for (int k = 0; k < 16; ++k)
                h_lds[l + 64 * k] = __uint_as_float((unsigned int)p[k]);
            if (l == 0)
                __hip_atomic_store(&h_flag, t, __ATOMIC_RELEASE,
                                   __HIP_MEMORY_SCOPE_WORKGROUP);
        }
    } else if (w <= 4) {
        // =================== COMPUTE WAVES ===================
        for (int t = 0; t < Tt; ++t) {
            while (__hip_atomic_load(&h_flag, __ATOMIC_ACQUIRE,
                                     __HIP_MEMORY_SCOPE_WORKGROUP) < t) {}
            float hv[16];
            #pragma unroll
            for (int k = 0; k < 16; ++k) hv[k] = h_lds[l + 64 * k];

            float arx = 0.f, ary = 0.f, azx = 0.f, azy = 0.f, anx = 0.f, any_ = 0.f;
            #pragma unroll
            for (int k = 0; k < 16; ++k) {
                const float h = hv[k];
                arx += h * wr[k].x; ary += h * wr[k].y;
                azx += h * wz[k].x; azy += h * wz[k].y;
                anx += h * wn[k].x; any_ += h * wn[k].y;
            }
            #pragma unroll
            for (int off = 1; off < 64; off <<= 1) {
                arx += __shfl_xor(arx, off); ary += __shfl_xor(ary, off);
                azx += __shfl_xor(azx, off); azy += __shfl_xor(azy, off);
                anx += __shfl_xor(anx, off); any_ += __shfl_xor(any_, off);
            }
            // lanes 0/1 finalize col c0 / c0+1 (all lanes compute, 2 write)
            const int p = l & 1;
            const float ar = p ? ary : arx;
            const float az = p ? azy : azx;
            const float an = p ? any_ : anx;
            const float bh = p ? bhn2.y : bhn2.x;
            const float xr = xp_lds[0 + cw * 2 + p];
            const float xz = xp_lds[8 + cw * 2 + p];
            const float xn = xp_lds[16 + cw * 2 + p];
            const float hp = h_lds[c0 + p];
            const float r = fast_sigmoid(xr + ar);
            const float z = fast_sigmoid(xz + az);
            const float n = fast_tanh(xn + r * (an + bh));
            const float hnew = (1.f - z) * n + z * hp;
            if (l < 2) {
                const unsigned long long packed =
                    ((unsigned long long)(unsigned int)(t + 1) << 32) |
                    (unsigned long long)__float_as_uint(hnew);
                __hip_atomic_store(&outbox[cw * 2 + l], packed,
                                   __ATOMIC_RELEASE, __HIP_MEMORY_SCOPE_WORKGROUP);
            }
        }
    } else {
        // =================== I/O WAVE ===================
        for (int t = 0; t < Tt; ++t) {
            const unsigned int want = (unsigned int)(t + 1);
            unsigned long long q = 0;
            for (;;) {
                if (l < 8)
                    q = __hip_atomic_load(&outbox[l], __ATOMIC_ACQUIRE,
                                          __HIP_MEMORY_SCOPE_WORKGROUP);
                const int ok = (l >= 8) || (((unsigned int)(q >> 32)) == want);
                if (__all(ok)) break;
            }
            unsigned long long* dst = hbuf + (size_t)((t + 1) & 1) * Dh;
            if (l < 8) {
                // 1) publish (8 lanes, one 64B line, single-hop tagged data)
                __hip_atomic_store(dst + b * 8 + l, q,
                                   __ATOMIC_RELAXED, __HIP_MEMORY_SCOPE_AGENT);
                // 2) ys[t][own 8 cols] (32B coalesced)
                ys[(size_t)t * Dh + b * 8 + l] = __uint_as_float((unsigned int)q);
            }
            // 3) prefetch xproj row t+1 into xp_lds (safe: overwritten only
            //    after all compute waves consumed row t — outbox gating)
            if (l < 24 && t + 1 < Tt) {
                xp_lds[l] = xproj[(size_t)(t + 1) * (3 * Dh)
                                  + (size_t)(l >> 3) * Dh + b * 8 + (l & 7)];
            }
            // acks/misses drain during next outbox spin — coupled to no one
        }
    }
}

// ---------------------------------------------------------------------------
// In-place layernorm over rows of y [T][Dh], matching jnp mean/var, eps=1e-6
// ---------------------------------------------------------------------------
__global__ __launch_bounds__(256)
void layernorm_ip(float* __restrict__ y, const float* __restrict__ sc,
                  const float* __restrict__ bi)
{
    __shared__ float red[8], red2[8], stat[2];
    const int row = blockIdx.x, tid = threadIdx.x;
    float4* yr = (float4*)(y + (size_t)row * Dh);
    float4 v = yr[tid];
    float s  = v.x + v.y + v.z + v.w;
    float s2 = v.x*v.x + v.y*v.y + v.z*v.z + v.w*v.w;
    #pragma unroll
    for (int off = 32; off > 0; off >>= 1) {
        s  += __shfl_down(s,  off);
        s2 += __shfl_down(s2, off);
    }
    if ((tid & 63) == 0) { red[tid >> 6] = s; red2[tid >> 6] = s2; }
    __syncthreads();
    if (tid == 0) {
        float ts = 0.f, t2 = 0.f;
        #pragma unroll
        for (int w = 0; w < 4; ++w) { ts += red[w]; t2 += red2[w]; }
        const float mu  = ts / (float)Dh;
        const float var = t2 / (float)Dh - mu * mu;
        stat[0] = mu;
        stat[1] = rsqrtf(var + 1e-6f);
    }
    __syncthreads();
    const float mu = stat[0], rstd = stat[1];
    const float4 s4 = ((const float4*)sc)[tid];
    const float4 b4 = ((const float4*)bi)[tid];
    v.x = (v.x - mu) * rstd * s4.x + b4.x;
    v.y = (v.y - mu) * rstd * s4.y + b4.y;
    v.z = (v.z - mu) * rstd * s4.z + b4.z;
    v.w = (v.w - mu) * rstd * s4.w + b4.w;
    yr[tid] = v;
}

// ---------------------------------------------------------------------------
extern "C" void kernel_launch(void* const* d_in, const int* in_sizes, int n_in,
                              void* d_out, int out_size, void* d_ws, size_t ws_size,
                              hipStream_t stream)
{
    const float* xs   = (const float*)d_in[0];
    const float* h0   = (const float*)d_in[1];
    const float* Wir  = (const float*)d_in[2];
    const float* Wiz  = (const float*)d_in[3];
    const float* Win  = (const float*)d_in[4];
    const float* bir  = (const float*)d_in[5];
    const float* biz  = (const float*)d_in[6];
    const float* bin_ = (const float*)d_in[7];
    const float* Whr  = (const float*)d_in[8];
    const float* Whz  = (const float*)d_in[9];
    const float* Whn  = (const float*)d_in[10];
    const float* bhn  = (const float*)d_in[11];
    const float* Wl   = (const float*)d_in[12];
    const float* bl   = (const float*)d_in[13];
    const float* ln_s = (const float*)d_in[14];
    const float* ln_b = (const float*)d_in[15];
    float* out = (float*)d_out;

    // workspace layout
    float* xproj = (float*)d_ws;                               // T*3*Dh
    float* ys    = xproj + (size_t)Tt * 3 * Dh;                // T*Dh
    unsigned long long* hbuf = (unsigned long long*)(ys + (size_t)Tt * Dh); // 2*Dh packed

    // Phase 0: pack init state (tag 0) into buffer 0
    pack_h0<<<4, 256, 0, stream>>>(h0, hbuf);

    // Phase 1: input projections (bias folded in)
    dim3 ggrid(Dh / 64, Tt / 64);
    gemm64<false, false><<<ggrid, 256, 0, stream>>>(xs, Wir, bir, nullptr,
                                                    xproj + 0 * Dh, Tt, Dh, Dh, 3 * Dh);
    gemm64<false, false><<<ggrid, 256, 0, stream>>>(xs, Wiz, biz, nullptr,
                                                    xproj + 1 * Dh, Tt, Dh, Dh, 3 * Dh);
    gemm64<false, false><<<ggrid, 256, 0, stream>>>(xs, Win, bin_, nullptr,
                                                    xproj + 2 * Dh, Tt, Dh, Dh, 3 * Dh);

    // Phase 2: sequential scan (persistent, co-resident, barrier-free)
    gru_rec<<<NB, 384, 0, stream>>>(xproj, Whr, Whz, Whn, bhn, ys, hbuf);

    // Phase 3: out = relu(ys) @ Wl + bl + xs, then in-place layernorm
    gemm64<true, true><<<ggrid, 256, 0, stream>>>(ys, Wl, bl, xs, out, Tt, Dh, Dh, Dh);
    layernorm_ip<<<Tt, 256, 0, stream>>>(out, ln_s, ln_b);
}